// Round 6
// baseline (242.995 us; speedup 1.0000x reference)
//
#include <hip/hip_runtime.h>

typedef __bf16 bf16;
typedef __attribute__((ext_vector_type(8))) __bf16 bf16x8;
typedef __attribute__((ext_vector_type(4))) __bf16 bf16x4;
typedef __attribute__((ext_vector_type(4))) float f32x4;

typedef __attribute__((address_space(1))) const void GvPtr;
typedef __attribute__((address_space(3))) void LdsPtr;

__device__ __forceinline__ void gload_lds16(const void* g, void* l) {
    __builtin_amdgcn_global_load_lds((GvPtr*)g, (LdsPtr*)l, 16, 0, 0);
}

// XCD-aware chunked remap (T1, m157/m192), R6: z-AWARE. Hardware assigns
// XCD = linear_block_id & 7 (round-robin, m09). Remap the FULL linear id
// (including z) so each XCD owns a contiguous chunk of the work order;
// bijective since every grid total here (1536/1024/512) is 0 mod 8.
// Effect on co-resident per-XCD footprint (all grids are 1-3 exact rounds):
//   QKV (gZ=1): identical to the R3 champion mapping (verified -5.3 us).
//   QK : 12 MB -> 6 MB (single z; k-panel 4 MB with 8x M-reuse).
//   PV : 20 MB -> 8 MB (single z; vt-panel 4 MB with 8x reuse).
// Mechanism (R3-verified): staging loads hit XCD-L2 -> the per-K-step
// vmcnt(0)+barrier drain shortens (L2 ~200 cy vs L3/HBM 500-900 cy).
struct WorkId { int z, pid; };
__device__ __forceinline__ WorkId xcd_work() {
    const int gX = gridDim.x, gY = gridDim.y, gZ = gridDim.z;
    const int G = gX * gY;
    const int T = G * gZ;
    const int lin = ((int)blockIdx.z * gY + (int)blockIdx.y) * gX
                    + (int)blockIdx.x;
    const int w = (lin & 7) * (T >> 3) + (lin >> 3);
    WorkId r;
    r.z = w / G;            // uniform, once per block
    r.pid = w - r.z * G;
    return r;
}

// ---------------------------------------------------------------------------
// ONE prep kernel: dtype-detect + X convert + weight transpose + bias + rowsum zero.
__global__ __launch_bounds__(256) void prep(
    const void* __restrict__ X,
    const void* __restrict__ Wq, const void* __restrict__ Wk,
    const void* __restrict__ Wv,
    const void* __restrict__ bq, const void* __restrict__ bk,
    const void* __restrict__ bv,
    bf16* __restrict__ Xb, bf16* __restrict__ wt, bf16* __restrict__ bb,
    float* __restrict__ rowsum)
{
    __shared__ int sflag;
    __shared__ bf16 t[32][33];
    const int tid = threadIdx.x;

    if (tid < 64) {
        const unsigned short* H = (const unsigned short*)X;
        int insane = 0;
        for (int i = tid; i < 128; i += 64) {
            int e = (H[2 * i] >> 7) & 0xFF;
            insane += (e >= 107 && e <= 131) ? 0 : 1;
        }
        #pragma unroll
        for (int off = 32; off > 0; off >>= 1)
            insane += __shfl_down(insane, off, 64);
        if (tid == 0) sflag = (insane >= 32) ? 1 : 0;
    }
    __syncthreads();
    const bool isf32 = (sflag != 0);

    const long b = blockIdx.x;
    if (b < 4096) {                       // X: 8M elems -> bf16, 8/thread
        long i = b * 256 + tid;
        if (isf32) {
            const float4* s = (const float4*)X;
            float4 a = s[2 * i], c = s[2 * i + 1];
            bf16x8 o;
            o[0] = (bf16)a.x; o[1] = (bf16)a.y; o[2] = (bf16)a.z; o[3] = (bf16)a.w;
            o[4] = (bf16)c.x; o[5] = (bf16)c.y; o[6] = (bf16)c.z; o[7] = (bf16)c.w;
            ((bf16x8*)Xb)[i] = o;
        } else {
            ((uint4*)Xb)[i] = ((const uint4*)X)[i];
        }
    } else if (b < 7168) {                // W transpose: [1024,1024] -> ^T
        const int wi = (int)((b - 4096) >> 10);
        const int id = (int)((b - 4096) & 1023);
        const void* src = (wi == 0) ? Wq : (wi == 1) ? Wk : Wv;
        bf16* dst = wt + (long)wi * 1024 * 1024;
        const int c0 = (id & 31) * 32, r0 = (id >> 5) * 32;
        const int tc = tid & 31, tr = tid >> 5;
        #pragma unroll
        for (int i = 0; i < 4; i++) {
            long idx = (long)(r0 + tr + i * 8) * 1024 + c0 + tc;
            t[tr + i * 8][tc] = isf32 ? (bf16)((const float*)src)[idx]
                                      : ((const bf16*)src)[idx];
        }
        __syncthreads();
        #pragma unroll
        for (int i = 0; i < 4; i++)
            dst[(long)(c0 + tr + i * 8) * 1024 + r0 + tc] = t[tc][tr + i * 8];
    } else if (b < 7180) {                // biases: 3 x 1024
        const int bi = (int)(b - 7168);
        const int wi = bi >> 2;
        const void* src = (wi == 0) ? bq : (wi == 1) ? bk : bv;
        const long i = (bi & 3) * 256 + tid;
        bb[wi * 1024 + i] = isf32 ? (bf16)((const float*)src)[i]
                                  : ((const bf16*)src)[i];
    } else {                              // rowsum zero: 8192 f32, 8 blocks
        const long i = (b - 7180) * 256 + tid;   // one float4 per thread
        ((float4*)rowsum)[i] = make_float4(0.f, 0.f, 0.f, 0.f);
    }
}

// ---------------------------------------------------------------------------
// BK=64 GEMM: C = scale*(A.B^T)+bias (or p'=exp(scale*.) with EXPSUM).
// 128x128 tile, 16x16x32 bf16 MFMA, global_load_lds w=16, GROUP_M=8 swizzle,
// mod-8 LDS chunk-rotation (verified conflict-free R6-R8).
// WAVES=4: 256 thr, wave tile 64x64 (acc 4x4) -> 4 blocks/CU.
// WAVES=8: 512 thr, wave tile 32x64 (acc 2x4) -> 2 blocks/CU = 16 waves/CU.
// Wave-count choice is PER-GEMM, measured:
//   QKV (1536 blocks): 8-wave, 890 TF (R3).
//   QK  (1024 blocks): 4-wave WINS -- 1 round @ 4/CU, no round-boundary
//     drain; 8-wave A/B'd at +2.6 us total (R4, reverted).
template <bool HAS_BIAS, bool OUT_F32, int WAVES, bool VSPLIT, bool EXPSUM>
__global__ __launch_bounds__(WAVES * 64, 4) void gemm_bt(
    const bf16* __restrict__ A, const bf16* __restrict__ B,
    void* __restrict__ Cv, const bf16* __restrict__ bias,
    bf16* __restrict__ vt, float* __restrict__ rowsum,
    int K, long lda, long ldb, long ldc, float scale,
    long strideA, long strideB, long strideC)
{
    constexpr int BK = 64;
    constexpr int MI = (WAVES == 4) ? 4 : 2;
    constexpr int NCH = (WAVES == 4) ? 4 : 2;     // gload issues per matrix
    constexpr int RSTEP = WAVES * 8;              // rows per issue
    constexpr int LSTEP = WAVES * 64 * 8;         // LDS elems per issue

    __shared__ bf16 As[128 * BK];  // 16 KB
    __shared__ bf16 Bs[128 * BK];  // 16 KB

    const int tid  = threadIdx.x;
    const int wave = tid >> 6;
    const int lane = tid & 63;
    const int r16  = lane & 15;
    const int quad = lane >> 4;

    const WorkId wk = xcd_work();
    const long z = wk.z;
    A += z * strideA;
    B += z * strideB;

    const int tX = gridDim.x;
    const int pid = wk.pid;
    const int groupSize = 8 * tX;
    const int gid = pid / groupSize;
    const int rem = pid % groupSize;
    const int tileM = (gid * 8 + (rem & 7)) * 128;
    const int tileN = (rem >> 3) * 128;

    const int waveM = (wave >> 1) * ((WAVES == 4) ? 64 : 32);
    const int waveN = (wave & 1) * 64;

    // Swizzled staging: phys slot p = tid + j*(WAVES*64); row = p>>3; logical
    // chunk c = ((p&7) - row) & 7, j-invariant (RSTEP is 0 mod 8).
    const int rS = tid >> 3;
    const int cOff = (((tid & 7) - (tid >> 3)) & 7) * 8;
    const bf16* Ag[NCH]; const bf16* Bg[NCH];
    #pragma unroll
    for (int j = 0; j < NCH; j++) {
        Ag[j] = A + (long)(tileM + rS + j * RSTEP) * lda + cOff;
        Bg[j] = B + (long)(tileN + rS + j * RSTEP) * ldb + cOff;
    }

    f32x4 acc[MI][4] = {};

    for (int k0 = 0; k0 < K; k0 += BK) {
        #pragma unroll
        for (int j = 0; j < NCH; j++) {
            gload_lds16(Ag[j], &As[tid * 8 + j * LSTEP]);
            gload_lds16(Bg[j], &Bs[tid * 8 + j * LSTEP]);
            Ag[j] += BK; Bg[j] += BK;
        }
        __syncthreads();

        #pragma unroll
        for (int ks = 0; ks < 2; ks++) {
            bf16x8 af[MI], bfv[4];
            #pragma unroll
            for (int i = 0; i < MI; i++) {
                const int row = waveM + i * 16 + r16;
                af[i] = *(const bf16x8*)
                    &As[row * 64 + ((ks * 4 + quad + row) & 7) * 8];
            }
            #pragma unroll
            for (int i = 0; i < 4; i++) {
                const int row = waveN + i * 16 + r16;
                bfv[i] = *(const bf16x8*)
                    &Bs[row * 64 + ((ks * 4 + quad + row) & 7) * 8];
            }
            #pragma unroll
            for (int mi = 0; mi < MI; mi++)
                #pragma unroll
                for (int ni = 0; ni < 4; ni++)
                    acc[mi][ni] = __builtin_amdgcn_mfma_f32_16x16x32_bf16(
                        af[mi], bfv[ni], acc[mi][ni], 0, 0, 0);
        }
        __syncthreads();
    }

    // C/D layout (m89/m91 verified): col = lane&15, row = quad*4 + r.
    const int crow0 = tileM + waveM + quad * 4;
    const int ccol0 = tileN + waveN + r16;

    if (EXPSUM) {
        float rs[MI][4];
        #pragma unroll
        for (int mi = 0; mi < MI; mi++)
            #pragma unroll
            for (int r = 0; r < 4; r++) rs[mi][r] = 0.0f;
        #pragma unroll
        for (int ni = 0; ni < 4; ni++) {
            const int col = ccol0 + ni * 16;
            #pragma unroll
            for (int mi = 0; mi < MI; mi++) {
                #pragma unroll
                for (int r = 0; r < 4; r++) {
                    const long row = crow0 + mi * 16 + r;
                    const float p = __expf(acc[mi][ni][r] * scale);
                    rs[mi][r] += p;
                    ((bf16*)Cv)[z * strideC + row * ldc + col] = (bf16)p;
                }
            }
        }
        #pragma unroll
        for (int mi = 0; mi < MI; mi++) {
            #pragma unroll
            for (int r = 0; r < 4; r++) {
                float s = rs[mi][r];
                s += __shfl_xor(s, 1, 64);
                s += __shfl_xor(s, 2, 64);
                s += __shfl_xor(s, 4, 64);
                s += __shfl_xor(s, 8, 64);
                if (r16 == 0)
                    atomicAdd(&rowsum[z * 2048 + crow0 + mi * 16 + r], s);
            }
        }
    } else if (VSPLIT && tileN >= 2048) {
        #pragma unroll
        for (int ni = 0; ni < 4; ni++) {
            const int col = ccol0 + ni * 16;
            const float bv = HAS_BIAS ? (float)bias[col] : 0.0f;
            const long colp = col - 2048;
            #pragma unroll
            for (int mi = 0; mi < MI; mi++) {
                const int grow = crow0 + mi * 16;
                const long bz = grow >> 11;
                const int srow = grow & 2047;
                bf16x4 o;
                #pragma unroll
                for (int r = 0; r < 4; r++)
                    o[r] = (bf16)(acc[mi][ni][r] * scale + bv);
                *(bf16x4*)&vt[(bz << 21) + colp * 2048 + srow] = o;
            }
        }
    } else {
        #pragma unroll
        for (int ni = 0; ni < 4; ni++) {
            const int col = ccol0 + ni * 16;
            const float bv = HAS_BIAS ? (float)bias[col] : 0.0f;
            #pragma unroll
            for (int mi = 0; mi < MI; mi++) {
                #pragma unroll
                for (int r = 0; r < 4; r++) {
                    const long row = crow0 + mi * 16 + r;
                    const float val = acc[mi][ni][r] * scale + bv;
                    if (OUT_F32) ((float*)Cv)[z * strideC + row * ldc + col] = val;
                    else         ((bf16*)Cv)[z * strideC + row * ldc + col] = (bf16)val;
                }
            }
        }
    }
}

// ---------------------------------------------------------------------------
// PV GEMM: 8 waves (512 thr), BK=128, 128x128 tile, wave tile 32x64.
// 64 KB LDS -> 2 blocks/CU = 16 waves/CU. out = (A.B^T) / rowsum[row].
// mod-16 chunk-rotation swizzle, j-invariant (32-row steps are 0 mod 16).
__global__ __launch_bounds__(512, 2) void gemm_pv(
    const bf16* __restrict__ A, const bf16* __restrict__ B,
    float* __restrict__ C, const float* __restrict__ rowsum,
    int K, long lda, long ldb, long ldc,
    long strideA, long strideB, long strideC)
{
    constexpr int BK = 128;
    __shared__ bf16 As[128 * BK];  // 32 KB
    __shared__ bf16 Bs[128 * BK];  // 32 KB

    const int tid  = threadIdx.x;
    const int wave = tid >> 6;
    const int lane = tid & 63;
    const int r16  = lane & 15;
    const int quad = lane >> 4;

    const WorkId wk = xcd_work();
    const long z = wk.z;
    A += z * strideA;
    B += z * strideB;

    const int tX = gridDim.x;
    const int pid = wk.pid;
    const int groupSize = 8 * tX;
    const int gid = pid / groupSize;
    const int rem = pid % groupSize;
    const int tileM = (gid * 8 + (rem & 7)) * 128;
    const int tileN = (rem >> 3) * 128;

    const int waveM = (wave >> 1) * 32;
    const int waveN = (wave & 1) * 64;

    const int rS = tid >> 4;                              // 0..31
    const int cOff = (((tid & 15) - (tid >> 4)) & 15) * 8;
    const bf16* Ag = A + (long)(tileM + rS) * lda + cOff;
    const bf16* Bg = B + (long)(tileN + rS) * ldb + cOff;

    f32x4 acc[2][4] = {};

    for (int k0 = 0; k0 < K; k0 += BK) {
        #pragma unroll
        for (int j = 0; j < 4; j++) {
            gload_lds16(Ag + (long)j * 32 * lda, &As[(tid + j * 512) * 8]);
            gload_lds16(Bg + (long)j * 32 * ldb, &Bs[(tid + j * 512) * 8]);
        }
        Ag += BK; Bg += BK;
        __syncthreads();

        #pragma unroll
        for (int ks = 0; ks < 4; ks++) {
            bf16x8 af[2], bfv[4];
            #pragma unroll
            for (int i = 0; i < 2; i++) {
                const int row = waveM + i * 16 + r16;
                af[i] = *(const bf16x8*)
                    &As[row * 128 + ((ks * 4 + quad + row) & 15) * 8];
            }
            #pragma unroll
            for (int i = 0; i < 4; i++) {
                const int row = waveN + i * 16 + r16;
                bfv[i] = *(const bf16x8*)
                    &Bs[row * 128 + ((ks * 4 + quad + row) & 15) * 8];
            }
            #pragma unroll
            for (int mi = 0; mi < 2; mi++)
                #pragma unroll
                for (int ni = 0; ni < 4; ni++)
                    acc[mi][ni] = __builtin_amdgcn_mfma_f32_16x16x32_bf16(
                        af[mi], bfv[ni], acc[mi][ni], 0, 0, 0);
        }
        __syncthreads();
    }

    const int crow0 = tileM + waveM + quad * 4;
    const int ccol0 = tileN + waveN + r16;
    float inv[2][4];
    #pragma unroll
    for (int mi = 0; mi < 2; mi++)
        #pragma unroll
        for (int r = 0; r < 4; r++)
            inv[mi][r] = 1.0f / rowsum[z * 2048 + crow0 + mi * 16 + r];
    #pragma unroll
    for (int ni = 0; ni < 4; ni++) {
        const int col = ccol0 + ni * 16;
        #pragma unroll
        for (int mi = 0; mi < 2; mi++)
            #pragma unroll
            for (int r = 0; r < 4; r++) {
                const long row = crow0 + mi * 16 + r;
                C[z * strideC + row * ldc + col] = acc[mi][ni][r] * inv[mi][r];
            }
    }
}

extern "C" void kernel_launch(void* const* d_in, const int* in_sizes, int n_in,
                              void* d_out, int out_size, void* d_ws, size_t ws_size,
                              hipStream_t stream) {
    constexpr int B = 4, S = 2048, D = 1024, N = 1024;
    constexpr long MS = (long)B * S;  // 8192

    const void* X  = d_in[0];
    const void* Wq = d_in[1];
    const void* bq = d_in[2];
    const void* Wk = d_in[3];
    const void* bk = d_in[4];
    const void* Wv = d_in[5];
    const void* bv = d_in[6];

    // workspace layout (~120 MB)
    char* w = (char*)d_ws;
    bf16*  Xb = (bf16*)w;                w += MS * D * sizeof(bf16);          // 16 MB
    bf16*  wt = (bf16*)w;                w += 3L * D * N * sizeof(bf16);      // 6 MB
    bf16*  bb = (bf16*)w;                w += 3L * N * sizeof(bf16) + 512;
    float* rowsum = (float*)w;           w += MS * sizeof(float);             // 32 KB
    bf16*  qkv = (bf16*)w;               w += MS * 3L * N * sizeof(bf16);     // 48 MB
    bf16*  vt = (bf16*)w;                w += MS * N * sizeof(bf16);          // 16 MB
    bf16*  sc = (bf16*)w;                                                    // 32 MB

    bf16* q = qkv;            // cols 0..1023 of [8192,3072]
    bf16* k = qkv + N;        // cols 1024..2047 (V cols go straight to vt)

    // 1) prep: detect + convert X/biases + transpose weights + zero rowsum
    prep<<<7188, 256, 0, stream>>>(X, Wq, Wk, Wv, bq, bk, bv, Xb, wt, bb, rowsum);

    // 2) fused QKV (8-wave blocks): q,k -> qkv; V -> vt transposed.
    //    1536 blocks @ 2/CU = exact 3 rounds, 16 waves/CU. z-aware remap
    //    reduces to the R3 champion mapping (gZ=1, bit-identical).
    gemm_bt<true, false, 8, true, false><<<dim3(3 * N / 128, MS / 128, 1), 512, 0, stream>>>(
        Xb, wt, qkv, bb, vt, nullptr, D, D, D, 3L * N, 1.0f, 0, 0, 0);

    // 3) p' = exp(q.k^T / 32) -> bf16 sc, + atomic row sums. 4-WAVE
    //    (R4 A/B: 8-wave +2.6 us, reverted): 1024 blocks @ 4/CU = exactly
    //    1 round. z-aware remap: per-XCD set 12 -> 6 MB (single batch).
    gemm_bt<false, false, 4, false, true><<<dim3(S / 128, S / 128, B), 256, 0, stream>>>(
        q, k, sc, nullptr, nullptr, rowsum, D, 3L * N, 3L * N, S, 0.03125f,
        (long)S * 3 * N, (long)S * 3 * N, (long)S * S);

    // 4) out = (p' . vt^T) / rowsum -> f32 d_out (8-wave BK=128 PV).
    //    512 blocks @ 2/CU = 1 round. z-aware remap: per-XCD 20 -> 8 MB.
    gemm_pv<<<dim3(N / 128, S / 128, B), 512, 0, stream>>>(
        sc, vt, (float*)d_out, rowsum, S, S, S, N,
        (long)S * S, (long)N * S, (long)S * N);
}

// Round 7
// 235.239 us; speedup vs baseline: 1.0330x; 1.0330x over previous
//
#include <hip/hip_runtime.h>

typedef __bf16 bf16;
typedef __attribute__((ext_vector_type(8))) __bf16 bf16x8;
typedef __attribute__((ext_vector_type(4))) __bf16 bf16x4;
typedef __attribute__((ext_vector_type(4))) float f32x4;

typedef __attribute__((address_space(1))) const void GvPtr;
typedef __attribute__((address_space(3))) void LdsPtr;

__device__ __forceinline__ void gload_lds16(const void* g, void* l) {
    __builtin_amdgcn_global_load_lds((GvPtr*)g, (LdsPtr*)l, 16, 0, 0);
}

// XCD-aware chunked remap (T1, m157/m192), applied PER-Z (R5 champion form).
// R3 verified on QKV (3 sequential rounds): FETCH 72->42.5 MB, -4 us/dispatch.
// R6 A/B'd a z-aware full-linear variant: +3.2 us total -> REVERTED.
// Lesson: locality remaps only pay on multi-round grids (QKV); QK/PV run
// single-round fully-co-resident, where remapping can't change what is
// simultaneously live.
__device__ __forceinline__ int xcd_remap(int pid0, int nwg) {
    return (pid0 & 7) * (nwg >> 3) + (pid0 >> 3);
}

// ---------------------------------------------------------------------------
// ONE prep kernel: dtype-detect + X convert + weight transpose + bias + rowsum zero.
__global__ __launch_bounds__(256) void prep(
    const void* __restrict__ X,
    const void* __restrict__ Wq, const void* __restrict__ Wk,
    const void* __restrict__ Wv,
    const void* __restrict__ bq, const void* __restrict__ bk,
    const void* __restrict__ bv,
    bf16* __restrict__ Xb, bf16* __restrict__ wt, bf16* __restrict__ bb,
    float* __restrict__ rowsum)
{
    __shared__ int sflag;
    __shared__ bf16 t[32][33];
    const int tid = threadIdx.x;

    if (tid < 64) {
        const unsigned short* H = (const unsigned short*)X;
        int insane = 0;
        for (int i = tid; i < 128; i += 64) {
            int e = (H[2 * i] >> 7) & 0xFF;
            insane += (e >= 107 && e <= 131) ? 0 : 1;
        }
        #pragma unroll
        for (int off = 32; off > 0; off >>= 1)
            insane += __shfl_down(insane, off, 64);
        if (tid == 0) sflag = (insane >= 32) ? 1 : 0;
    }
    __syncthreads();
    const bool isf32 = (sflag != 0);

    const long b = blockIdx.x;
    if (b < 4096) {                       // X: 8M elems -> bf16, 8/thread
        long i = b * 256 + tid;
        if (isf32) {
            const float4* s = (const float4*)X;
            float4 a = s[2 * i], c = s[2 * i + 1];
            bf16x8 o;
            o[0] = (bf16)a.x; o[1] = (bf16)a.y; o[2] = (bf16)a.z; o[3] = (bf16)a.w;
            o[4] = (bf16)c.x; o[5] = (bf16)c.y; o[6] = (bf16)c.z; o[7] = (bf16)c.w;
            ((bf16x8*)Xb)[i] = o;
        } else {
            ((uint4*)Xb)[i] = ((const uint4*)X)[i];
        }
    } else if (b < 7168) {                // W transpose: [1024,1024] -> ^T
        const int wi = (int)((b - 4096) >> 10);
        const int id = (int)((b - 4096) & 1023);
        const void* src = (wi == 0) ? Wq : (wi == 1) ? Wk : Wv;
        bf16* dst = wt + (long)wi * 1024 * 1024;
        const int c0 = (id & 31) * 32, r0 = (id >> 5) * 32;
        const int tc = tid & 31, tr = tid >> 5;
        #pragma unroll
        for (int i = 0; i < 4; i++) {
            long idx = (long)(r0 + tr + i * 8) * 1024 + c0 + tc;
            t[tr + i * 8][tc] = isf32 ? (bf16)((const float*)src)[idx]
                                      : ((const bf16*)src)[idx];
        }
        __syncthreads();
        #pragma unroll
        for (int i = 0; i < 4; i++)
            dst[(long)(c0 + tr + i * 8) * 1024 + r0 + tc] = t[tc][tr + i * 8];
    } else if (b < 7180) {                // biases: 3 x 1024
        const int bi = (int)(b - 7168);
        const int wi = bi >> 2;
        const void* src = (wi == 0) ? bq : (wi == 1) ? bk : bv;
        const long i = (bi & 3) * 256 + tid;
        bb[wi * 1024 + i] = isf32 ? (bf16)((const float*)src)[i]
                                  : ((const bf16*)src)[i];
    } else {                              // rowsum zero: 8192 f32, 8 blocks
        const long i = (b - 7180) * 256 + tid;   // one float4 per thread
        ((float4*)rowsum)[i] = make_float4(0.f, 0.f, 0.f, 0.f);
    }
}

// ---------------------------------------------------------------------------
// BK=64 GEMM: C = scale*(A.B^T)+bias (or p'=exp(scale*.) with EXPSUM).
// 128x128 tile, 16x16x32 bf16 MFMA, global_load_lds w=16, GROUP_M=8 swizzle,
// mod-8 LDS chunk-rotation (verified conflict-free R6-R8).
// WAVES=4: 256 thr, wave tile 64x64 (acc 4x4) -> 4 blocks/CU.
// WAVES=8: 512 thr, wave tile 32x64 (acc 2x4) -> 2 blocks/CU = 16 waves/CU.
// Wave-count choice is PER-GEMM, measured:
//   QKV (1536 blocks): 8-wave, 890 TF (R3).
//   QK  (1024 blocks): 4-wave WINS -- 1 round @ 4/CU, no round-boundary
//     drain; 8-wave A/B'd at +2.6 us total (R4, reverted).
template <bool HAS_BIAS, bool OUT_F32, int WAVES, bool VSPLIT, bool EXPSUM>
__global__ __launch_bounds__(WAVES * 64, 4) void gemm_bt(
    const bf16* __restrict__ A, const bf16* __restrict__ B,
    void* __restrict__ Cv, const bf16* __restrict__ bias,
    bf16* __restrict__ vt, float* __restrict__ rowsum,
    int K, long lda, long ldb, long ldc, float scale,
    long strideA, long strideB, long strideC)
{
    constexpr int BK = 64;
    constexpr int MI = (WAVES == 4) ? 4 : 2;
    constexpr int NCH = (WAVES == 4) ? 4 : 2;     // gload issues per matrix
    constexpr int RSTEP = WAVES * 8;              // rows per issue
    constexpr int LSTEP = WAVES * 64 * 8;         // LDS elems per issue

    __shared__ bf16 As[128 * BK];  // 16 KB
    __shared__ bf16 Bs[128 * BK];  // 16 KB

    const int tid  = threadIdx.x;
    const int wave = tid >> 6;
    const int lane = tid & 63;
    const int r16  = lane & 15;
    const int quad = lane >> 4;

    const long z = blockIdx.z;
    A += z * strideA;
    B += z * strideB;

    const int tX = gridDim.x;
    const int pid0 = blockIdx.y * tX + blockIdx.x;
    const int pid = xcd_remap(pid0, tX * (int)gridDim.y);
    const int groupSize = 8 * tX;
    const int gid = pid / groupSize;
    const int rem = pid % groupSize;
    const int tileM = (gid * 8 + (rem & 7)) * 128;
    const int tileN = (rem >> 3) * 128;

    const int waveM = (wave >> 1) * ((WAVES == 4) ? 64 : 32);
    const int waveN = (wave & 1) * 64;

    // Swizzled staging: phys slot p = tid + j*(WAVES*64); row = p>>3; logical
    // chunk c = ((p&7) - row) & 7, j-invariant (RSTEP is 0 mod 8).
    const int rS = tid >> 3;
    const int cOff = (((tid & 7) - (tid >> 3)) & 7) * 8;
    const bf16* Ag[NCH]; const bf16* Bg[NCH];
    #pragma unroll
    for (int j = 0; j < NCH; j++) {
        Ag[j] = A + (long)(tileM + rS + j * RSTEP) * lda + cOff;
        Bg[j] = B + (long)(tileN + rS + j * RSTEP) * ldb + cOff;
    }

    f32x4 acc[MI][4] = {};

    for (int k0 = 0; k0 < K; k0 += BK) {
        #pragma unroll
        for (int j = 0; j < NCH; j++) {
            gload_lds16(Ag[j], &As[tid * 8 + j * LSTEP]);
            gload_lds16(Bg[j], &Bs[tid * 8 + j * LSTEP]);
            Ag[j] += BK; Bg[j] += BK;
        }
        __syncthreads();

        #pragma unroll
        for (int ks = 0; ks < 2; ks++) {
            bf16x8 af[MI], bfv[4];
            #pragma unroll
            for (int i = 0; i < MI; i++) {
                const int row = waveM + i * 16 + r16;
                af[i] = *(const bf16x8*)
                    &As[row * 64 + ((ks * 4 + quad + row) & 7) * 8];
            }
            #pragma unroll
            for (int i = 0; i < 4; i++) {
                const int row = waveN + i * 16 + r16;
                bfv[i] = *(const bf16x8*)
                    &Bs[row * 64 + ((ks * 4 + quad + row) & 7) * 8];
            }
            #pragma unroll
            for (int mi = 0; mi < MI; mi++)
                #pragma unroll
                for (int ni = 0; ni < 4; ni++)
                    acc[mi][ni] = __builtin_amdgcn_mfma_f32_16x16x32_bf16(
                        af[mi], bfv[ni], acc[mi][ni], 0, 0, 0);
        }
        __syncthreads();
    }

    // C/D layout (m89/m91 verified): col = lane&15, row = quad*4 + r.
    const int crow0 = tileM + waveM + quad * 4;
    const int ccol0 = tileN + waveN + r16;

    if (EXPSUM) {
        float rs[MI][4];
        #pragma unroll
        for (int mi = 0; mi < MI; mi++)
            #pragma unroll
            for (int r = 0; r < 4; r++) rs[mi][r] = 0.0f;
        #pragma unroll
        for (int ni = 0; ni < 4; ni++) {
            const int col = ccol0 + ni * 16;
            #pragma unroll
            for (int mi = 0; mi < MI; mi++) {
                #pragma unroll
                for (int r = 0; r < 4; r++) {
                    const long row = crow0 + mi * 16 + r;
                    const float p = __expf(acc[mi][ni][r] * scale);
                    rs[mi][r] += p;
                    ((bf16*)Cv)[z * strideC + row * ldc + col] = (bf16)p;
                }
            }
        }
        #pragma unroll
        for (int mi = 0; mi < MI; mi++) {
            #pragma unroll
            for (int r = 0; r < 4; r++) {
                float s = rs[mi][r];
                s += __shfl_xor(s, 1, 64);
                s += __shfl_xor(s, 2, 64);
                s += __shfl_xor(s, 4, 64);
                s += __shfl_xor(s, 8, 64);
                if (r16 == 0)
                    atomicAdd(&rowsum[z * 2048 + crow0 + mi * 16 + r], s);
            }
        }
    } else if (VSPLIT && tileN >= 2048) {
        #pragma unroll
        for (int ni = 0; ni < 4; ni++) {
            const int col = ccol0 + ni * 16;
            const float bv = HAS_BIAS ? (float)bias[col] : 0.0f;
            const long colp = col - 2048;
            #pragma unroll
            for (int mi = 0; mi < MI; mi++) {
                const int grow = crow0 + mi * 16;
                const long bz = grow >> 11;
                const int srow = grow & 2047;
                bf16x4 o;
                #pragma unroll
                for (int r = 0; r < 4; r++)
                    o[r] = (bf16)(acc[mi][ni][r] * scale + bv);
                *(bf16x4*)&vt[(bz << 21) + colp * 2048 + srow] = o;
            }
        }
    } else {
        #pragma unroll
        for (int ni = 0; ni < 4; ni++) {
            const int col = ccol0 + ni * 16;
            const float bv = HAS_BIAS ? (float)bias[col] : 0.0f;
            #pragma unroll
            for (int mi = 0; mi < MI; mi++) {
                #pragma unroll
                for (int r = 0; r < 4; r++) {
                    const long row = crow0 + mi * 16 + r;
                    const float val = acc[mi][ni][r] * scale + bv;
                    if (OUT_F32) ((float*)Cv)[z * strideC + row * ldc + col] = val;
                    else         ((bf16*)Cv)[z * strideC + row * ldc + col] = (bf16)val;
                }
            }
        }
    }
}

// ---------------------------------------------------------------------------
// PV GEMM: 8 waves (512 thr), BK=128, 128x128 tile, wave tile 32x64.
// 64 KB LDS -> 2 blocks/CU = 16 waves/CU. out = (A.B^T) / rowsum[row].
// mod-16 chunk-rotation swizzle, j-invariant (32-row steps are 0 mod 16).
__global__ __launch_bounds__(512, 2) void gemm_pv(
    const bf16* __restrict__ A, const bf16* __restrict__ B,
    float* __restrict__ C, const float* __restrict__ rowsum,
    int K, long lda, long ldb, long ldc,
    long strideA, long strideB, long strideC)
{
    constexpr int BK = 128;
    __shared__ bf16 As[128 * BK];  // 32 KB
    __shared__ bf16 Bs[128 * BK];  // 32 KB

    const int tid  = threadIdx.x;
    const int wave = tid >> 6;
    const int lane = tid & 63;
    const int r16  = lane & 15;
    const int quad = lane >> 4;

    const long z = blockIdx.z;
    A += z * strideA;
    B += z * strideB;

    const int tX = gridDim.x;
    const int pid0 = blockIdx.y * tX + blockIdx.x;
    const int pid = xcd_remap(pid0, tX * (int)gridDim.y);
    const int groupSize = 8 * tX;
    const int gid = pid / groupSize;
    const int rem = pid % groupSize;
    const int tileM = (gid * 8 + (rem & 7)) * 128;
    const int tileN = (rem >> 3) * 128;

    const int waveM = (wave >> 1) * 32;
    const int waveN = (wave & 1) * 64;

    const int rS = tid >> 4;                              // 0..31
    const int cOff = (((tid & 15) - (tid >> 4)) & 15) * 8;
    const bf16* Ag = A + (long)(tileM + rS) * lda + cOff;
    const bf16* Bg = B + (long)(tileN + rS) * ldb + cOff;

    f32x4 acc[2][4] = {};

    for (int k0 = 0; k0 < K; k0 += BK) {
        #pragma unroll
        for (int j = 0; j < 4; j++) {
            gload_lds16(Ag + (long)j * 32 * lda, &As[(tid + j * 512) * 8]);
            gload_lds16(Bg + (long)j * 32 * ldb, &Bs[(tid + j * 512) * 8]);
        }
        Ag += BK; Bg += BK;
        __syncthreads();

        #pragma unroll
        for (int ks = 0; ks < 4; ks++) {
            bf16x8 af[2], bfv[4];
            #pragma unroll
            for (int i = 0; i < 2; i++) {
                const int row = waveM + i * 16 + r16;
                af[i] = *(const bf16x8*)
                    &As[row * 128 + ((ks * 4 + quad + row) & 15) * 8];
            }
            #pragma unroll
            for (int i = 0; i < 4; i++) {
                const int row = waveN + i * 16 + r16;
                bfv[i] = *(const bf16x8*)
                    &Bs[row * 128 + ((ks * 4 + quad + row) & 15) * 8];
            }
            #pragma unroll
            for (int mi = 0; mi < 2; mi++)
                #pragma unroll
                for (int ni = 0; ni < 4; ni++)
                    acc[mi][ni] = __builtin_amdgcn_mfma_f32_16x16x32_bf16(
                        af[mi], bfv[ni], acc[mi][ni], 0, 0, 0);
        }
        __syncthreads();
    }

    const int crow0 = tileM + waveM + quad * 4;
    const int ccol0 = tileN + waveN + r16;
    float inv[2][4];
    #pragma unroll
    for (int mi = 0; mi < 2; mi++)
        #pragma unroll
        for (int r = 0; r < 4; r++)
            inv[mi][r] = 1.0f / rowsum[z * 2048 + crow0 + mi * 16 + r];
    #pragma unroll
    for (int ni = 0; ni < 4; ni++) {
        const int col = ccol0 + ni * 16;
        #pragma unroll
        for (int mi = 0; mi < 2; mi++)
            #pragma unroll
            for (int r = 0; r < 4; r++) {
                const long row = crow0 + mi * 16 + r;
                C[z * strideC + row * ldc + col] = acc[mi][ni][r] * inv[mi][r];
            }
    }
}

extern "C" void kernel_launch(void* const* d_in, const int* in_sizes, int n_in,
                              void* d_out, int out_size, void* d_ws, size_t ws_size,
                              hipStream_t stream) {
    constexpr int B = 4, S = 2048, D = 1024, N = 1024;
    constexpr long MS = (long)B * S;  // 8192

    const void* X  = d_in[0];
    const void* Wq = d_in[1];
    const void* bq = d_in[2];
    const void* Wk = d_in[3];
    const void* bk = d_in[4];
    const void* Wv = d_in[5];
    const void* bv = d_in[6];

    // workspace layout (~120 MB)
    char* w = (char*)d_ws;
    bf16*  Xb = (bf16*)w;                w += MS * D * sizeof(bf16);          // 16 MB
    bf16*  wt = (bf16*)w;                w += 3L * D * N * sizeof(bf16);      // 6 MB
    bf16*  bb = (bf16*)w;                w += 3L * N * sizeof(bf16) + 512;
    float* rowsum = (float*)w;           w += MS * sizeof(float);             // 32 KB
    bf16*  qkv = (bf16*)w;               w += MS * 3L * N * sizeof(bf16);     // 48 MB
    bf16*  vt = (bf16*)w;                w += MS * N * sizeof(bf16);          // 16 MB
    bf16*  sc = (bf16*)w;                                                    // 32 MB

    bf16* q = qkv;            // cols 0..1023 of [8192,3072]
    bf16* k = qkv + N;        // cols 1024..2047 (V cols go straight to vt)

    // 1) prep: detect + convert X/biases + transpose weights + zero rowsum
    prep<<<7188, 256, 0, stream>>>(X, Wq, Wk, Wv, bq, bk, bv, Xb, wt, bb, rowsum);

    // 2) fused QKV (8-wave blocks): q,k -> qkv; V -> vt transposed.
    //    1536 blocks @ 2/CU = exact 3 rounds, 16 waves/CU. XCD chunk = 192
    //    blocks = exactly one GROUP_M group (M-tiles 0-7 x all 24 N-tiles).
    gemm_bt<true, false, 8, true, false><<<dim3(3 * N / 128, MS / 128, 1), 512, 0, stream>>>(
        Xb, wt, qkv, bb, vt, nullptr, D, D, D, 3L * N, 1.0f, 0, 0, 0);

    // 3) p' = exp(q.k^T / 32) -> bf16 sc, + atomic row sums. 4-WAVE
    //    (R4 A/B: 8-wave +2.6 us, reverted): 1024 blocks @ 4/CU = exactly
    //    1 round, all blocks co-resident, no round-boundary drain.
    gemm_bt<false, false, 4, false, true><<<dim3(S / 128, S / 128, B), 256, 0, stream>>>(
        q, k, sc, nullptr, nullptr, rowsum, D, 3L * N, 3L * N, S, 0.03125f,
        (long)S * 3 * N, (long)S * 3 * N, (long)S * S);

    // 4) out = (p' . vt^T) / rowsum -> f32 d_out (8-wave BK=128 PV)
    gemm_pv<<<dim3(N / 128, S / 128, B), 512, 0, stream>>>(
        sc, vt, (float*)d_out, rowsum, S, S, S, N,
        (long)S * S, (long)N * S, (long)S * N);
}